// Round 3
// baseline (976.217 us; speedup 1.0000x reference)
//
#include <hip/hip_runtime.h>

#define N_NODES 100000
#define N_EDGES 1600000
#define D 64
#define N_BBOX 4096
#define CAP 64          // per-bbox-node slot capacity (deg ~ Poisson(16))
#define NBUCKET 1563    // ceil(100000/64)
#define BUCKET_CAP 2048 // lambda=1024, 32 sigma of headroom

__device__ __forceinline__ float readlane_f(float v, int l) {
  return __int_as_float(__builtin_amdgcn_readlane(__float_as_int(v), l));
}
__device__ __forceinline__ int readlane_i(int v, int l) {
  return __builtin_amdgcn_readlane(v, l);
}
__device__ __forceinline__ int bperm(int srclane, int v) {
  return __builtin_amdgcn_ds_bpermute(srclane << 2, v);
}
__device__ __forceinline__ float lrelu(float v) {
  return fmaxf(v, 0.01f * v);  // neg_slope 0.01 > 0
}

// ---- mark bbox nodes with their canonical output position (pos+1) ----
__global__ __launch_bounds__(256) void mark_kernel(const int* __restrict__ bbox,
                                                   int* __restrict__ bbox_pos) {
  int t = blockIdx.x * blockDim.x + threadIdx.x;
  if (t < N_BBOX) bbox_pos[bbox[t]] = t + 1;  // dup nodes: one writer wins
}

// ---- single pass over edges: coarse bucket binning + bbox slot fill ----
__global__ __launch_bounds__(256) void bin_kernel(
    const int* __restrict__ src, const int* __restrict__ dst,
    const int* __restrict__ bbox_pos, int* __restrict__ bucket_cnt,
    int* __restrict__ bucketed, int* __restrict__ bcnt,
    int* __restrict__ bslots) {
  int e = blockIdx.x * blockDim.x + threadIdx.x;
  if (e >= N_EDGES) return;
  int s = src[e], d = dst[e];
  int b = d >> 6, loc = d & 63;
  int p = atomicAdd(&bucket_cnt[b], 1);
  if (p < BUCKET_CAP) bucketed[(size_t)b * BUCKET_CAP + p] = s | (loc << 17);
  int t = bbox_pos[d];
  if (t > 0) {
    int q = atomicAdd(&bcnt[t - 1], 1);
    if (q < CAP) bslots[(t - 1) * CAP + q] = s;
  }
}

// ---- layer-1 aggregation: per-bucket LDS accumulator ----
__global__ __launch_bounds__(256) void agg1_kernel(const float* __restrict__ x,
                                                   const int* __restrict__ bucket_cnt,
                                                   const int* __restrict__ bucketed,
                                                   float* __restrict__ agg) {
  __shared__ float acc[64 * 64];  // 16 KB; lane j -> addr loc*64+j (2-way, free)
  const int b = blockIdx.x;
  const int t = threadIdx.x;
  const int lane = t & 63;
  const int w = t >> 6;

  for (int i = t; i < 64 * 64; i += 256) acc[i] = 0.f;
  __syncthreads();

  int n = bucket_cnt[b];
  n = (n > BUCKET_CAP) ? BUCKET_CAP : n;
  const int* ebase = bucketed + (size_t)b * BUCKET_CAP;

  for (int c0 = w * 64; c0 < n; c0 += 256) {
    const int myv = (c0 + lane < n) ? ebase[c0 + lane] : 0;  // coalesced 256B
    const int m = (n - c0 < 64) ? (n - c0) : 64;
    int j = 0;
    for (; j + 8 <= m; j += 8) {
      float v[8];
      int loc[8];
#pragma unroll
      for (int u = 0; u < 8; u++) {
        const int pv = readlane_i(myv, j + u);
        loc[u] = pv >> 17;
        v[u] = x[(size_t)(pv & 0x1FFFF) * D + lane];  // 8 loads in flight
      }
#pragma unroll
      for (int u = 0; u < 8; u++) atomicAdd(&acc[loc[u] * 64 + lane], v[u]);
    }
    for (; j < m; j++) {
      const int pv = readlane_i(myv, j);
      atomicAdd(&acc[(pv >> 17) * 64 + lane], x[(size_t)(pv & 0x1FFFF) * D + lane]);
    }
  }
  __syncthreads();

  const int node0 = b * 64;
  for (int i = w; i < 64; i += 4) {
    const int node = node0 + i;
    if (node < N_NODES) agg[(size_t)node * D + lane] = acc[i * 64 + lane];
  }
}

// ---- layer-1 dense: h = lrelu(agg@W1rel + b1 + x@W1root), in place ----
__global__ __launch_bounds__(256, 1) void dense1_kernel(
    const float* __restrict__ x, const float* __restrict__ W1rel,
    const float* __restrict__ b1, const float* __restrict__ W1root,
    float* __restrict__ hbuf) {
  const int lane = threadIdx.x & 63;
  const int wid = (blockIdx.x * blockDim.x + threadIdx.x) >> 6;
  const int nw = (gridDim.x * blockDim.x) >> 6;

  float wrel[D], wroot[D];
#pragma unroll
  for (int k = 0; k < D; k++) {
    wrel[k] = W1rel[k * D + lane];
    wroot[k] = W1root[k * D + lane];
  }
  const float bj = b1[lane];

  for (int i = wid; i < N_NODES; i += nw) {
    const float a = hbuf[(size_t)i * D + lane];
    const float xi = x[(size_t)i * D + lane];
    float s0 = 0.f, s1 = 0.f, s2 = 0.f, s3 = 0.f;
#pragma unroll
    for (int k = 0; k < D; k += 2) {
      s0 += readlane_f(a, k) * wrel[k];
      s1 += readlane_f(xi, k) * wroot[k];
      s2 += readlane_f(a, k + 1) * wrel[k + 1];
      s3 += readlane_f(xi, k + 1) * wroot[k + 1];
    }
    hbuf[(size_t)i * D + lane] = lrelu(bj + ((s0 + s1) + (s2 + s3)));
  }
}

// ---- layer-2: fused gather + dense, bbox rows only ----
__global__ __launch_bounds__(256, 1) void layer2_kernel(
    const float4* __restrict__ h4, const int* __restrict__ bbox_pos,
    const int* __restrict__ bcnt, const int* __restrict__ bslots,
    const int* __restrict__ bbox, const float* __restrict__ W2rel,
    const float* __restrict__ b2, const float* __restrict__ W2root,
    float* __restrict__ out) {
  const int t = (blockIdx.x * blockDim.x + threadIdx.x) >> 6;
  if (t >= N_BBOX) return;
  const int lane = threadIdx.x & 63;
  const int g = lane >> 4, c = lane & 15;

  float wrel[D], wroot[D];
#pragma unroll
  for (int k = 0; k < D; k++) {
    wrel[k] = W2rel[k * D + lane];
    wroot[k] = W2root[k * D + lane];
  }
  const float bj = b2[lane];

  const int node = __builtin_amdgcn_readfirstlane(bbox[t]);
  const int canon = __builtin_amdgcn_readfirstlane(bbox_pos[node]) - 1;
  int n = bcnt[canon];
  n = (n > CAP) ? CAP : n;
  const int myslot = (lane < n) ? bslots[canon * CAP + lane] : 0;

  float4 acc = make_float4(0.f, 0.f, 0.f, 0.f);
  for (int e0 = 0; e0 < n; e0 += 32) {
    int idx[8], s[8];
    float4 v[8];
#pragma unroll
    for (int u = 0; u < 8; u++) {
      idx[u] = e0 + u * 4 + g;
      s[u] = bperm(idx[u], myslot);
    }
#pragma unroll
    for (int u = 0; u < 8; u++) {
      v[u] = make_float4(0.f, 0.f, 0.f, 0.f);
      if (idx[u] < n) v[u] = h4[(size_t)s[u] * 16 + c];
    }
#pragma unroll
    for (int u = 0; u < 8; u++) {
      acc.x += v[u].x; acc.y += v[u].y; acc.z += v[u].z; acc.w += v[u].w;
    }
  }
  acc.x += __shfl_xor(acc.x, 16); acc.y += __shfl_xor(acc.y, 16);
  acc.z += __shfl_xor(acc.z, 16); acc.w += __shfl_xor(acc.w, 16);
  acc.x += __shfl_xor(acc.x, 32); acc.y += __shfl_xor(acc.y, 32);
  acc.z += __shfl_xor(acc.z, 32); acc.w += __shfl_xor(acc.w, 32);
  // agg element a_{4c+u} is component u of lane c (replicated across groups)

  const float hi = ((const float*)h4)[(size_t)node * D + lane];
  float s0 = 0.f, s1 = 0.f, s2 = 0.f, s3 = 0.f;
#pragma unroll
  for (int k = 0; k < D; k += 2) {
    const float a0 = (k & 2) ? readlane_f(acc.z, k >> 2) : readlane_f(acc.x, k >> 2);
    const float a1 = ((k + 1) & 2) ? readlane_f(acc.w, (k + 1) >> 2)
                                   : readlane_f(acc.y, (k + 1) >> 2);
    s0 += a0 * wrel[k];
    s1 += readlane_f(hi, k) * wroot[k];
    s2 += a1 * wrel[k + 1];
    s3 += readlane_f(hi, k + 1) * wroot[k + 1];
  }
  out[(size_t)t * D + lane] = lrelu(bj + ((s0 + s1) + (s2 + s3)));
}

// ---------------- launch ----------------

extern "C" void kernel_launch(void* const* d_in, const int* in_sizes, int n_in,
                              void* d_out, int out_size, void* d_ws, size_t ws_size,
                              hipStream_t stream) {
  const float* x = (const float*)d_in[0];
  const int* ei = (const int*)d_in[1];
  const int* src = ei;
  const int* dst = ei + N_EDGES;
  const int* bbox = (const int*)d_in[2];
  const float* W1rel = (const float*)d_in[3];
  const float* b1 = (const float*)d_in[4];
  const float* W1root = (const float*)d_in[5];
  const float* W2rel = (const float*)d_in[6];
  const float* b2 = (const float*)d_in[7];
  const float* W2root = (const float*)d_in[8];
  float* out = (float*)d_out;

  char* ws = (char*)d_ws;
  size_t off = 0;
  auto alloc = [&](size_t bytes) -> char* {
    char* p = ws + off;
    off = (off + bytes + 511) & ~(size_t)511;
    return p;
  };
  // contiguous zero-init region: bbox_pos + bucket_cnt + bcnt
  int* bbox_pos = (int*)alloc(N_NODES * sizeof(int));
  int* bucket_cnt = (int*)alloc(NBUCKET * sizeof(int));
  int* bcnt = (int*)alloc(N_BBOX * sizeof(int));
  char* zero_end = ws + off;
  int* bucketed = (int*)alloc((size_t)NBUCKET * BUCKET_CAP * sizeof(int));
  int* bslots = (int*)alloc((size_t)N_BBOX * CAP * sizeof(int));
  float* hbuf = (float*)alloc((size_t)N_NODES * D * sizeof(float));  // agg -> h1

  hipMemsetAsync(bbox_pos, 0, (size_t)(zero_end - (char*)bbox_pos), stream);
  mark_kernel<<<(N_BBOX + 255) / 256, 256, 0, stream>>>(bbox, bbox_pos);
  bin_kernel<<<(N_EDGES + 255) / 256, 256, 0, stream>>>(
      src, dst, bbox_pos, bucket_cnt, bucketed, bcnt, bslots);
  agg1_kernel<<<NBUCKET, 256, 0, stream>>>(x, bucket_cnt, bucketed, hbuf);
  dense1_kernel<<<2048, 256, 0, stream>>>(x, W1rel, b1, W1root, hbuf);
  layer2_kernel<<<(N_BBOX + 3) / 4, 256, 0, stream>>>(
      (const float4*)hbuf, bbox_pos, bcnt, bslots, bbox, W2rel, b2, W2root, out);
}

// Round 4
// 309.741 us; speedup vs baseline: 3.1517x; 3.1517x over previous
//
#include <hip/hip_runtime.h>

#define N_NODES 100000
#define N_EDGES 1600000
#define D 64
#define N_BBOX 4096
#define CAP 64           // per-node slot capacity; deg ~ Poisson(16), P(>=64) ~ 1e-20
#define NBUCKET 1563     // ceil(100000 / 64)
#define BUCKET_CAP 1536  // Poisson(1024) +16 sigma
#define CNT_STRIDE 16    // one bucket counter per 64B line (atomic ping-pong fix)

__device__ __forceinline__ float readlane_f(float v, int l) {
  return __int_as_float(__builtin_amdgcn_readlane(__float_as_int(v), l));
}
__device__ __forceinline__ int bperm(int srclane, int v) {
  return __builtin_amdgcn_ds_bpermute(srclane << 2, v);
}
__device__ __forceinline__ float lrelu(float v) {
  return fmaxf(v, 0.01f * v);  // neg_slope 0.01 > 0
}

// ---- pass 1: bin edges by dst>>6; cursors padded to one per cache line ----
__global__ __launch_bounds__(256) void bin_kernel(const int* __restrict__ src,
                                                  const int* __restrict__ dst,
                                                  int* __restrict__ bucket_cnt,
                                                  int* __restrict__ bucketed) {
  int e = blockIdx.x * blockDim.x + threadIdx.x;
  if (e >= N_EDGES) return;
  int s = src[e], d = dst[e];
  int b = d >> 6;
  int p = atomicAdd(&bucket_cnt[b * CNT_STRIDE], 1);
  if (p < BUCKET_CAP) bucketed[b * BUCKET_CAP + p] = s | ((d & 63) << 17);
}

// ---- pass 2: bucket -> per-node slots via LDS scatter, coalesced writeout ----
__global__ __launch_bounds__(256) void build_slots_kernel(
    const int* __restrict__ bucket_cnt, const int* __restrict__ bucketed,
    int* __restrict__ cnt, int* __restrict__ slots) {
  __shared__ int lcnt[64];
  __shared__ int lslots[64 * 65];  // stride 65: scattered ds_write bank spread
  const int b = blockIdx.x;
  const int t = threadIdx.x;
  if (t < 64) lcnt[t] = 0;
  __syncthreads();

  int n = bucket_cnt[b * CNT_STRIDE];
  n = (n > BUCKET_CAP) ? BUCKET_CAP : n;
  const int* ebase = bucketed + b * BUCKET_CAP;
  for (int e = t; e < n; e += 256) {  // coalesced bucket read
    int pv = ebase[e];
    int loc = pv >> 17;
    int p = atomicAdd(&lcnt[loc], 1);  // LDS atomic, ~4-way collisions
    if (p < CAP) lslots[loc * 65 + p] = pv & 0x1FFFF;
  }
  __syncthreads();

  const int node0 = b * 64;
  if (t < 64 && node0 + t < N_NODES) cnt[node0 + t] = lcnt[t];
  for (int i = t; i < 64 * 64; i += 256) {  // coalesced 16KB tile write
    int loc = i >> 6;
    if (node0 + loc < N_NODES)
      slots[(size_t)(node0 + loc) * CAP + (i & 63)] = lslots[loc * 65 + (i & 63)];
  }
}

// ---- layer-1 gather: one wave per node, 4 edges/instr, 32 edges in flight ----
__global__ __launch_bounds__(256) void gather1_kernel(const float4* __restrict__ x4,
                                                      const int* __restrict__ cnt,
                                                      const int* __restrict__ slots,
                                                      float4* __restrict__ agg4) {
  const int wid = (blockIdx.x * blockDim.x + threadIdx.x) >> 6;
  if (wid >= N_NODES) return;
  const int lane = threadIdx.x & 63;
  const int g = lane >> 4, c = lane & 15;

  int n = cnt[wid];
  n = (n > CAP) ? CAP : n;
  const int myslot = (lane < n) ? slots[(size_t)wid * CAP + lane] : 0;

  float4 acc = make_float4(0.f, 0.f, 0.f, 0.f);
  for (int e0 = 0; e0 < n; e0 += 32) {
    int idx[8], s[8];
    float4 v[8];
#pragma unroll
    for (int u = 0; u < 8; u++) {
      idx[u] = e0 + u * 4 + g;
      s[u] = bperm(idx[u], myslot);
    }
#pragma unroll
    for (int u = 0; u < 8; u++) {
      v[u] = make_float4(0.f, 0.f, 0.f, 0.f);
      if (idx[u] < n) v[u] = x4[(size_t)s[u] * 16 + c];
    }
#pragma unroll
    for (int u = 0; u < 8; u++) {
      acc.x += v[u].x; acc.y += v[u].y; acc.z += v[u].z; acc.w += v[u].w;
    }
  }
  acc.x += __shfl_xor(acc.x, 16); acc.y += __shfl_xor(acc.y, 16);
  acc.z += __shfl_xor(acc.z, 16); acc.w += __shfl_xor(acc.w, 16);
  acc.x += __shfl_xor(acc.x, 32); acc.y += __shfl_xor(acc.y, 32);
  acc.z += __shfl_xor(acc.z, 32); acc.w += __shfl_xor(acc.w, 32);
  if (g == 0) agg4[(size_t)wid * 16 + c] = acc;
}

// ---- layer-1 dense: h = lrelu(agg@W1rel + b1 + x@W1root), in place ----
__global__ __launch_bounds__(256, 1) void dense1_kernel(
    const float* __restrict__ x, const float* __restrict__ W1rel,
    const float* __restrict__ b1, const float* __restrict__ W1root,
    float* __restrict__ hbuf) {
  const int lane = threadIdx.x & 63;
  const int wid = (blockIdx.x * blockDim.x + threadIdx.x) >> 6;
  const int nw = (gridDim.x * blockDim.x) >> 6;

  float wrel[D], wroot[D];
#pragma unroll
  for (int k = 0; k < D; k++) {
    wrel[k] = W1rel[k * D + lane];
    wroot[k] = W1root[k * D + lane];
  }
  const float bj = b1[lane];

  for (int i = wid; i < N_NODES; i += nw) {
    const float a = hbuf[(size_t)i * D + lane];
    const float xi = x[(size_t)i * D + lane];
    float s0 = 0.f, s1 = 0.f, s2 = 0.f, s3 = 0.f;
#pragma unroll
    for (int k = 0; k < D; k += 2) {
      s0 += readlane_f(a, k) * wrel[k];
      s1 += readlane_f(xi, k) * wroot[k];
      s2 += readlane_f(a, k + 1) * wrel[k + 1];
      s3 += readlane_f(xi, k + 1) * wroot[k + 1];
    }
    hbuf[(size_t)i * D + lane] = lrelu(bj + ((s0 + s1) + (s2 + s3)));
  }
}

// ---- layer-2: fused gather + dense, bbox rows only ----
__global__ __launch_bounds__(256, 1) void layer2_kernel(
    const float4* __restrict__ h4, const int* __restrict__ cnt,
    const int* __restrict__ slots, const int* __restrict__ bbox,
    const float* __restrict__ W2rel, const float* __restrict__ b2,
    const float* __restrict__ W2root, float* __restrict__ out) {
  const int t = (blockIdx.x * blockDim.x + threadIdx.x) >> 6;
  if (t >= N_BBOX) return;
  const int lane = threadIdx.x & 63;
  const int g = lane >> 4, c = lane & 15;

  float wrel[D], wroot[D];
#pragma unroll
  for (int k = 0; k < D; k++) {
    wrel[k] = W2rel[k * D + lane];
    wroot[k] = W2root[k * D + lane];
  }
  const float bj = b2[lane];

  const int node = __builtin_amdgcn_readfirstlane(bbox[t]);
  int n = cnt[node];
  n = (n > CAP) ? CAP : n;
  const int myslot = (lane < n) ? slots[(size_t)node * CAP + lane] : 0;

  float4 acc = make_float4(0.f, 0.f, 0.f, 0.f);
  for (int e0 = 0; e0 < n; e0 += 32) {
    int idx[8], s[8];
    float4 v[8];
#pragma unroll
    for (int u = 0; u < 8; u++) {
      idx[u] = e0 + u * 4 + g;
      s[u] = bperm(idx[u], myslot);
    }
#pragma unroll
    for (int u = 0; u < 8; u++) {
      v[u] = make_float4(0.f, 0.f, 0.f, 0.f);
      if (idx[u] < n) v[u] = h4[(size_t)s[u] * 16 + c];
    }
#pragma unroll
    for (int u = 0; u < 8; u++) {
      acc.x += v[u].x; acc.y += v[u].y; acc.z += v[u].z; acc.w += v[u].w;
    }
  }
  acc.x += __shfl_xor(acc.x, 16); acc.y += __shfl_xor(acc.y, 16);
  acc.z += __shfl_xor(acc.z, 16); acc.w += __shfl_xor(acc.w, 16);
  acc.x += __shfl_xor(acc.x, 32); acc.y += __shfl_xor(acc.y, 32);
  acc.z += __shfl_xor(acc.z, 32); acc.w += __shfl_xor(acc.w, 32);
  // agg element a_{4c+u} is component u of lane c (replicated across groups)

  const float hi = ((const float*)h4)[(size_t)node * D + lane];
  float s0 = 0.f, s1 = 0.f, s2 = 0.f, s3 = 0.f;
#pragma unroll
  for (int k = 0; k < D; k += 2) {
    const float a0 = (k & 2) ? readlane_f(acc.z, k >> 2) : readlane_f(acc.x, k >> 2);
    const float a1 = ((k + 1) & 2) ? readlane_f(acc.w, (k + 1) >> 2)
                                   : readlane_f(acc.y, (k + 1) >> 2);
    s0 += a0 * wrel[k];
    s1 += readlane_f(hi, k) * wroot[k];
    s2 += a1 * wrel[k + 1];
    s3 += readlane_f(hi, k + 1) * wroot[k + 1];
  }
  out[(size_t)t * D + lane] = lrelu(bj + ((s0 + s1) + (s2 + s3)));
}

// ---------------- launch ----------------

extern "C" void kernel_launch(void* const* d_in, const int* in_sizes, int n_in,
                              void* d_out, int out_size, void* d_ws, size_t ws_size,
                              hipStream_t stream) {
  const float* x = (const float*)d_in[0];
  const int* ei = (const int*)d_in[1];
  const int* src = ei;
  const int* dst = ei + N_EDGES;
  const int* bbox = (const int*)d_in[2];
  const float* W1rel = (const float*)d_in[3];
  const float* b1 = (const float*)d_in[4];
  const float* W1root = (const float*)d_in[5];
  const float* W2rel = (const float*)d_in[6];
  const float* b2 = (const float*)d_in[7];
  const float* W2root = (const float*)d_in[8];
  float* out = (float*)d_out;

  char* ws = (char*)d_ws;
  size_t off = 0;
  auto alloc = [&](size_t bytes) -> char* {
    char* p = ws + off;
    off = (off + bytes + 511) & ~(size_t)511;
    return p;
  };
  int* bucket_cnt = (int*)alloc((size_t)NBUCKET * CNT_STRIDE * sizeof(int));  // 100 KB
  int* cnt = (int*)alloc(N_NODES * sizeof(int));
  int* slots = (int*)alloc((size_t)N_NODES * CAP * sizeof(int));  // 25.6 MB
  // bucketed (9.6 MB) overlaid with hbuf (25.6 MB): bucketed dead before gather1
  char* ovl = alloc((size_t)N_NODES * D * sizeof(float));
  int* bucketed = (int*)ovl;
  float* hbuf = (float*)ovl;

  hipMemsetAsync(bucket_cnt, 0, (size_t)NBUCKET * CNT_STRIDE * sizeof(int), stream);
  bin_kernel<<<(N_EDGES + 255) / 256, 256, 0, stream>>>(src, dst, bucket_cnt, bucketed);
  build_slots_kernel<<<NBUCKET, 256, 0, stream>>>(bucket_cnt, bucketed, cnt, slots);
  gather1_kernel<<<(N_NODES + 3) / 4, 256, 0, stream>>>(
      (const float4*)x, cnt, slots, (float4*)hbuf);
  dense1_kernel<<<2048, 256, 0, stream>>>(x, W1rel, b1, W1root, hbuf);
  layer2_kernel<<<(N_BBOX + 3) / 4, 256, 0, stream>>>(
      (const float4*)hbuf, cnt, slots, bbox, W2rel, b2, W2root, out);
}

// Round 5
// 213.980 us; speedup vs baseline: 4.5622x; 1.4475x over previous
//
#include <hip/hip_runtime.h>

#define N_NODES 100000
#define N_EDGES 1600000
#define D 64
#define N_BBOX 4096
#define CAP 64  // per-node slot capacity; deg ~ Poisson(16), P(>=64) ~ 1e-20

__device__ __forceinline__ float readlane_f(float v, int l) {
  return __int_as_float(__builtin_amdgcn_readlane(__float_as_int(v), l));
}
__device__ __forceinline__ int bperm(int srclane, int v) {
  return __builtin_amdgcn_ds_bpermute(srclane << 2, v);
}
__device__ __forceinline__ float lrelu(float v) {
  return fmaxf(v, 0.01f * v);  // neg_slope 0.01 > 0
}

// ---- mark bbox nodes (they need h1 too: root term + layer-2 gather) ----
__global__ __launch_bounds__(256) void mark_kernel(const int* __restrict__ bbox,
                                                   int* __restrict__ is_bbox,
                                                   int* __restrict__ needed) {
  int t = blockIdx.x * blockDim.x + threadIdx.x;
  if (t < N_BBOX) {
    int n = bbox[t];
    is_bbox[n] = 1;
    needed[n] = 1;
  }
}

// ---- mark h1 rows needed by layer 2: srcs of edges landing on bbox nodes ----
__global__ __launch_bounds__(256) void mark_needed_kernel(
    const int* __restrict__ src, const int* __restrict__ dst,
    const int* __restrict__ is_bbox, int* __restrict__ needed) {
  int e = blockIdx.x * blockDim.x + threadIdx.x;
  if (e >= N_EDGES) return;
  int d = dst[e];
  if (is_bbox[d]) needed[src[e]] = 1;  // benign race: all write 1
}

// ---- direct per-node slot fill, filtered to needed dst (~50% of edges) ----
__global__ __launch_bounds__(256) void fill_kernel(const int* __restrict__ src,
                                                   const int* __restrict__ dst,
                                                   const int* __restrict__ needed,
                                                   int* __restrict__ cnt,
                                                   int* __restrict__ slots) {
  int e = blockIdx.x * blockDim.x + threadIdx.x;
  if (e >= N_EDGES) return;
  int d = dst[e];
  if (!needed[d]) return;
  int p = atomicAdd(&cnt[d], 1);
  if (p < CAP) slots[(size_t)d * CAP + p] = src[e];
}

// ---- layer-1 gather (needed nodes only): 4 edges/instr, 32 in flight ----
__global__ __launch_bounds__(256) void gather1_kernel(const float4* __restrict__ x4,
                                                      const int* __restrict__ needed,
                                                      const int* __restrict__ cnt,
                                                      const int* __restrict__ slots,
                                                      float4* __restrict__ agg4) {
  const int wid = (blockIdx.x * blockDim.x + threadIdx.x) >> 6;
  if (wid >= N_NODES) return;
  if (!needed[wid]) return;
  const int lane = threadIdx.x & 63;
  const int g = lane >> 4, c = lane & 15;

  int n = cnt[wid];
  n = (n > CAP) ? CAP : n;
  const int myslot = (lane < n) ? slots[(size_t)wid * CAP + lane] : 0;

  float4 acc = make_float4(0.f, 0.f, 0.f, 0.f);
  for (int e0 = 0; e0 < n; e0 += 32) {
    int idx[8], s[8];
    float4 v[8];
#pragma unroll
    for (int u = 0; u < 8; u++) {
      idx[u] = e0 + u * 4 + g;
      s[u] = bperm(idx[u], myslot);
    }
#pragma unroll
    for (int u = 0; u < 8; u++) {
      v[u] = make_float4(0.f, 0.f, 0.f, 0.f);
      if (idx[u] < n) v[u] = x4[(size_t)s[u] * 16 + c];
    }
#pragma unroll
    for (int u = 0; u < 8; u++) {
      acc.x += v[u].x; acc.y += v[u].y; acc.z += v[u].z; acc.w += v[u].w;
    }
  }
  acc.x += __shfl_xor(acc.x, 16); acc.y += __shfl_xor(acc.y, 16);
  acc.z += __shfl_xor(acc.z, 16); acc.w += __shfl_xor(acc.w, 16);
  acc.x += __shfl_xor(acc.x, 32); acc.y += __shfl_xor(acc.y, 32);
  acc.z += __shfl_xor(acc.z, 32); acc.w += __shfl_xor(acc.w, 32);
  if (g == 0) agg4[(size_t)wid * 16 + c] = acc;
}

// ---- layer-1 dense (needed rows only): h = lrelu(agg@W1rel + b1 + x@W1root) ----
__global__ __launch_bounds__(256, 1) void dense1_kernel(
    const float* __restrict__ x, const int* __restrict__ needed,
    const float* __restrict__ W1rel, const float* __restrict__ b1,
    const float* __restrict__ W1root, float* __restrict__ hbuf) {
  const int lane = threadIdx.x & 63;
  const int wid = (blockIdx.x * blockDim.x + threadIdx.x) >> 6;
  const int nw = (gridDim.x * blockDim.x) >> 6;

  float wrel[D], wroot[D];
#pragma unroll
  for (int k = 0; k < D; k++) {
    wrel[k] = W1rel[k * D + lane];
    wroot[k] = W1root[k * D + lane];
  }
  const float bj = b1[lane];

  for (int i = wid; i < N_NODES; i += nw) {
    if (!needed[i]) continue;
    const float a = hbuf[(size_t)i * D + lane];
    const float xi = x[(size_t)i * D + lane];
    float s0 = 0.f, s1 = 0.f, s2 = 0.f, s3 = 0.f;
#pragma unroll
    for (int k = 0; k < D; k += 2) {
      s0 += readlane_f(a, k) * wrel[k];
      s1 += readlane_f(xi, k) * wroot[k];
      s2 += readlane_f(a, k + 1) * wrel[k + 1];
      s3 += readlane_f(xi, k + 1) * wroot[k + 1];
    }
    hbuf[(size_t)i * D + lane] = lrelu(bj + ((s0 + s1) + (s2 + s3)));
  }
}

// ---- layer-2: fused gather + dense, bbox rows only ----
// Layer-2 gather over node's slots needs ONLY edges into bbox nodes; slots for
// bbox nodes are exact (bbox nodes are needed), and every src in them has a
// valid h1 row (marked needed), so reading slots directly is correct.
__global__ __launch_bounds__(256, 1) void layer2_kernel(
    const float4* __restrict__ h4, const int* __restrict__ cnt,
    const int* __restrict__ slots, const int* __restrict__ bbox,
    const float* __restrict__ W2rel, const float* __restrict__ b2,
    const float* __restrict__ W2root, float* __restrict__ out) {
  const int t = (blockIdx.x * blockDim.x + threadIdx.x) >> 6;
  if (t >= N_BBOX) return;
  const int lane = threadIdx.x & 63;
  const int g = lane >> 4, c = lane & 15;

  float wrel[D], wroot[D];
#pragma unroll
  for (int k = 0; k < D; k++) {
    wrel[k] = W2rel[k * D + lane];
    wroot[k] = W2root[k * D + lane];
  }
  const float bj = b2[lane];

  const int node = __builtin_amdgcn_readfirstlane(bbox[t]);
  int n = cnt[node];
  n = (n > CAP) ? CAP : n;
  const int myslot = (lane < n) ? slots[(size_t)node * CAP + lane] : 0;

  float4 acc = make_float4(0.f, 0.f, 0.f, 0.f);
  for (int e0 = 0; e0 < n; e0 += 32) {
    int idx[8], s[8];
    float4 v[8];
#pragma unroll
    for (int u = 0; u < 8; u++) {
      idx[u] = e0 + u * 4 + g;
      s[u] = bperm(idx[u], myslot);
    }
#pragma unroll
    for (int u = 0; u < 8; u++) {
      v[u] = make_float4(0.f, 0.f, 0.f, 0.f);
      if (idx[u] < n) v[u] = h4[(size_t)s[u] * 16 + c];
    }
#pragma unroll
    for (int u = 0; u < 8; u++) {
      acc.x += v[u].x; acc.y += v[u].y; acc.z += v[u].z; acc.w += v[u].w;
    }
  }
  acc.x += __shfl_xor(acc.x, 16); acc.y += __shfl_xor(acc.y, 16);
  acc.z += __shfl_xor(acc.z, 16); acc.w += __shfl_xor(acc.w, 16);
  acc.x += __shfl_xor(acc.x, 32); acc.y += __shfl_xor(acc.y, 32);
  acc.z += __shfl_xor(acc.z, 32); acc.w += __shfl_xor(acc.w, 32);
  // agg element a_{4c+u} is component u of lane c (replicated across groups)

  const float hi = ((const float*)h4)[(size_t)node * D + lane];
  float s0 = 0.f, s1 = 0.f, s2 = 0.f, s3 = 0.f;
#pragma unroll
  for (int k = 0; k < D; k += 2) {
    const float a0 = (k & 2) ? readlane_f(acc.z, k >> 2) : readlane_f(acc.x, k >> 2);
    const float a1 = ((k + 1) & 2) ? readlane_f(acc.w, (k + 1) >> 2)
                                   : readlane_f(acc.y, (k + 1) >> 2);
    s0 += a0 * wrel[k];
    s1 += readlane_f(hi, k) * wroot[k];
    s2 += a1 * wrel[k + 1];
    s3 += readlane_f(hi, k + 1) * wroot[k + 1];
  }
  out[(size_t)t * D + lane] = lrelu(bj + ((s0 + s1) + (s2 + s3)));
}

// ---------------- launch ----------------

extern "C" void kernel_launch(void* const* d_in, const int* in_sizes, int n_in,
                              void* d_out, int out_size, void* d_ws, size_t ws_size,
                              hipStream_t stream) {
  const float* x = (const float*)d_in[0];
  const int* ei = (const int*)d_in[1];
  const int* src = ei;
  const int* dst = ei + N_EDGES;
  const int* bbox = (const int*)d_in[2];
  const float* W1rel = (const float*)d_in[3];
  const float* b1 = (const float*)d_in[4];
  const float* W1root = (const float*)d_in[5];
  const float* W2rel = (const float*)d_in[6];
  const float* b2 = (const float*)d_in[7];
  const float* W2root = (const float*)d_in[8];
  float* out = (float*)d_out;

  char* ws = (char*)d_ws;
  size_t off = 0;
  auto alloc = [&](size_t bytes) -> char* {
    char* p = ws + off;
    off = (off + bytes + 511) & ~(size_t)511;
    return p;
  };
  // contiguous zero region: is_bbox + needed + cnt (1.2 MB, one memset)
  int* is_bbox = (int*)alloc(N_NODES * sizeof(int));
  int* needed = (int*)alloc(N_NODES * sizeof(int));
  int* cnt = (int*)alloc(N_NODES * sizeof(int));
  char* zero_end = ws + off;
  int* slots = (int*)alloc((size_t)N_NODES * CAP * sizeof(int));   // 25.6 MB
  float* hbuf = (float*)alloc((size_t)N_NODES * D * sizeof(float)); // 25.6 MB

  hipMemsetAsync(is_bbox, 0, (size_t)(zero_end - (char*)is_bbox), stream);
  mark_kernel<<<(N_BBOX + 255) / 256, 256, 0, stream>>>(bbox, is_bbox, needed);
  mark_needed_kernel<<<(N_EDGES + 255) / 256, 256, 0, stream>>>(src, dst, is_bbox,
                                                                needed);
  fill_kernel<<<(N_EDGES + 255) / 256, 256, 0, stream>>>(src, dst, needed, cnt,
                                                         slots);
  gather1_kernel<<<(N_NODES + 3) / 4, 256, 0, stream>>>(
      (const float4*)x, needed, cnt, slots, (float4*)hbuf);
  dense1_kernel<<<2048, 256, 0, stream>>>(x, needed, W1rel, b1, W1root, hbuf);
  layer2_kernel<<<(N_BBOX + 3) / 4, 256, 0, stream>>>(
      (const float4*)hbuf, cnt, slots, bbox, W2rel, b2, W2root, out);
}